// Round 1
// 6374.725 us; speedup vs baseline: 1.0679x; 1.0679x over previous
//
#include <hip/hip_runtime.h>
#include <math.h>

// Problem constants: B=64, L=256, E=1024, H=1024
#define TWOH    2048
#define FIVEH   5120
#define NSTEPS  255
#define NBLK    64
#define LDS_KQ  120                       // kq rows of W_l kept in LDS (of 128)
#define LDS_BYTES (LDS_KQ * 80 * 8 * 2)   // 153600 B

typedef __attribute__((ext_vector_type(8))) short short8;
typedef __attribute__((ext_vector_type(8))) unsigned short ushort8;
typedef __attribute__((ext_vector_type(4))) float f32x4;

__device__ __forceinline__ float bf2f(unsigned short u) {
    union { unsigned int i; float f; } v; v.i = ((unsigned int)u) << 16; return v.f;
}
__device__ __forceinline__ unsigned short f2bf(float f) {
    union { float f; unsigned int u; } v; v.f = f;
    return (unsigned short)((v.u + 0x7FFFu + ((v.u >> 16) & 1u)) >> 16);
}
__device__ __forceinline__ short8 cvt8(float4 u0, float4 u1) {
    short8 s;
    s[0] = (short)f2bf(u0.x); s[1] = (short)f2bf(u0.y);
    s[2] = (short)f2bf(u0.z); s[3] = (short)f2bf(u0.w);
    s[4] = (short)f2bf(u1.x); s[5] = (short)f2bf(u1.y);
    s[6] = (short)f2bf(u1.z); s[7] = (short)f2bf(u1.w);
    return s;
}
__device__ __forceinline__ float sigf(float x) { return 1.0f / (1.0f + expf(-x)); }

__global__ void zero_stats(float* __restrict__ p) {
    p[blockIdx.x * 256 + threadIdx.x] = 0.0f;
}
__global__ void init_ctr(unsigned int* __restrict__ c) {
    if (threadIdx.x == 0) *c = 0u;
}

// Pack W[K,N] fp32 -> MFMA-B-fragment layout: out[kq][n][j] = bf16(W[kq*8+j][n])
__global__ void pack_w(const float* __restrict__ W, unsigned short* __restrict__ out, int N)
{
    const int kq = blockIdx.x;
    for (int n = threadIdx.x; n < N; n += 256) {
        ushort8 o;
#pragma unroll
        for (int j = 0; j < 8; j++)
            o[j] = f2bf(W[(size_t)(kq * 8 + j) * N + n]);
        *(ushort8*)&out[((size_t)kq * N + n) * 8] = o;
    }
}

// ---------------------------------------------------------------------------
// P = sentence @ W_word (bias dropped: cancels through BN). Unchanged.
// ---------------------------------------------------------------------------
__global__ __launch_bounds__(256) void gemm_bn_mfma(
    const float* __restrict__ A, const unsigned short* __restrict__ Bpk,
    unsigned short* __restrict__ h_out, unsigned short* __restrict__ c_out,
    float* __restrict__ sumb, float* __restrict__ sqb)
{
    const int tid = threadIdx.x;
    const int wave = tid >> 6, lane = tid & 63;
    const int q = lane >> 4, r = lane & 15;
    const int m0 = blockIdx.y * 128 + (wave >> 1) * 64;
    const int n0 = blockIdx.x * 128 + (wave & 1) * 64;

    f32x4 acc[4][4];
#pragma unroll
    for (int i = 0; i < 4; i++)
#pragma unroll
        for (int j = 0; j < 4; j++) acc[i][j] = (f32x4)0.0f;

    for (int k0 = 0; k0 < 1024; k0 += 32) {
        const int kl = k0 + q * 8;
        short8 a[4], b[4];
#pragma unroll
        for (int mi = 0; mi < 4; mi++) {
            const float* ap = A + (size_t)(m0 + mi * 16 + r) * 1024 + kl;
            a[mi] = cvt8(*(const float4*)ap, *(const float4*)(ap + 4));
        }
#pragma unroll
        for (int ni = 0; ni < 4; ni++)
            b[ni] = *(const short8*)&Bpk[((size_t)(kl >> 3) * TWOH + n0 + ni * 16 + r) * 8];
#pragma unroll
        for (int mi = 0; mi < 4; mi++)
#pragma unroll
            for (int ni = 0; ni < 4; ni++)
                acc[mi][ni] = __builtin_amdgcn_mfma_f32_16x16x32_bf16(a[mi], b[ni], acc[mi][ni], 0, 0, 0);
    }

#pragma unroll
    for (int ni = 0; ni < 4; ni++) {
        float s = 0.0f, qq = 0.0f;
#pragma unroll
        for (int mi = 0; mi < 4; mi++)
#pragma unroll
            for (int rg = 0; rg < 4; rg++) {
                const float v = acc[mi][ni][rg];
                s += v; qq += v * v;
            }
        s += __shfl_xor(s, 16); s += __shfl_xor(s, 32);
        qq += __shfl_xor(qq, 16); qq += __shfl_xor(qq, 32);
        if (lane < 16) {
            atomicAdd(&sumb[n0 + ni * 16 + r], s);
            atomicAdd(&sqb[n0 + ni * 16 + r], qq);
        }
    }

    const bool is_h = (n0 < 1024);
    unsigned short* dst = is_h ? h_out : c_out;
    const int cb = is_h ? n0 : n0 - 1024;
#pragma unroll
    for (int mi = 0; mi < 4; mi++)
#pragma unroll
        for (int rg = 0; rg < 4; rg++) {
            const size_t row = (size_t)(m0 + mi * 16 + q * 4 + rg);
#pragma unroll
            for (int ni = 0; ni < 4; ni++)
                dst[row * 1024 + cb + ni * 16 + r] = f2bf(acc[mi][ni][rg]);
        }
}

__global__ void bn_finalize(const float* __restrict__ sumb, const float* __restrict__ sqb,
                            const float* __restrict__ gamma, const float* __restrict__ beta,
                            float* __restrict__ scale, float* __restrict__ shift)
{
    const int c = blockIdx.x * 256 + threadIdx.x;  // grid 8
    const float inv_n = 1.0f / 16384.0f;
    const float mean = sumb[c] * inv_n;
    const float var = sqb[c] * inv_n - mean * mean;
    const float sc = gamma[c] * rsqrtf(var + 1e-5f);
    scale[c] = sc;
    shift[c] = beta[c] - mean * sc;
}

__global__ void bn_apply(unsigned short* __restrict__ hs, unsigned short* __restrict__ cs,
                         const float* __restrict__ scale, const float* __restrict__ shift)
{
    const bool ish = blockIdx.x < 8192;
    unsigned short* p = ish ? hs : cs;
    const size_t base = ((size_t)(blockIdx.x & 8191) * 256 + threadIdx.x) * 8;
    const int col = (int)(base & 1023);
    const int cb = ish ? col : col + 1024;
    ushort8 v = *(ushort8*)&p[base];
#pragma unroll
    for (int e = 0; e < 8; e++)
        v[e] = f2bf(bf2f(v[e]) * scale[cb + e] + shift[cb + e]);
    *(ushort8*)&p[base] = v;
}

// ---------------------------------------------------------------------------
// Persistent chain kernel: all 255 reduce steps in one launch.
//  - 64 blocks (one per CU guaranteed resident), block owns 16 h-cols x 5 gates.
//  - W_l (K rows 0..959 of the left half) pinned in LDS for the whole kernel;
//    K rows 960..1023 + the whole right half stream from L2/L3.
//  - 4 waves split M (16 batch rows each): no cross-wave reduction, acc = 20 VGPRs.
//  - c chain lives in registers (4 cells/thread); h chain is bf16 ping-pong in
//    global (bit-exact vs fp32-store-then-convert: h is only consumed as bf16).
//  - One device-scope barrier per step (monotonic counter). Right-half GEMM
//    (A = word j, static) runs BEFORE the wait -> overlaps stragglers.
// ---------------------------------------------------------------------------
__global__ __launch_bounds__(256, 1) void spinn_chain(
    const unsigned short* __restrict__ h_sent,
    const unsigned short* __restrict__ c_sent,
    const unsigned short* __restrict__ Wpk,   // [256 kq][5120][8] bf16
    const float* __restrict__ b_red,
    unsigned short* __restrict__ hchain,      // [2][64][1024] bf16 ping-pong
    unsigned int* __restrict__ ctr,
    float* __restrict__ out)                  // [64][1024] fp32
{
    extern __shared__ unsigned short Wl[];    // [LDS_KQ][80][8]
    const int tid = threadIdx.x;
    const int w = tid >> 6, lane = tid & 63;
    const int q = lane >> 4, r = lane & 15;
    const int c0 = blockIdx.x * 16;

    // ---- one-time: this block's W_l slice (80 cols x LDS_KQ kq-rows) into LDS
    for (int idx = tid; idx < LDS_KQ * 80; idx += 256) {
        const int kq = idx / 80, c = idx - kq * 80;
        const int g = c >> 4, cc = c & 15;
        *(ushort8*)&Wl[(size_t)idx * 8] =
            *(const ushort8*)&Wpk[((size_t)kq * FIVEH + g * 1024 + c0 + cc) * 8];
    }

    // ---- per-thread constants: bias, cell coordinates
    float breg[5];
#pragma unroll
    for (int g = 0; g < 5; g++) breg[g] = b_red[g * 1024 + c0 + r];

    // cells owned by this thread: (m = 16w + 4q + rg, col = c0 + r), rg=0..3
    float creg[4];
#pragma unroll
    for (int rg = 0; rg < 4; rg++) {
        const int m = 16 * w + 4 * q + rg;
        creg[rg] = bf2f(c_sent[(size_t)m * 256 * 1024 + c0 + r]);           // word 0
        hchain[(size_t)m * 1024 + c0 + r] = h_sent[(size_t)m * 256 * 1024 + c0 + r];
    }
    __syncthreads();
    if (tid == 0) {
        __threadfence();
        __hip_atomic_fetch_add(ctr, 1u, __ATOMIC_RELEASE, __HIP_MEMORY_SCOPE_AGENT);
    }

    const int arow = 16 * w + r;  // batch row this lane loads for the A-fragment

    for (int j = 1; j <= NSTEPS; j++) {
        f32x4 acc[5];
#pragma unroll
        for (int g = 0; g < 5; g++) acc[g] = (f32x4)0.0f;

        // prefetch right-child c (word j) for the elementwise phase
        float crv[4];
#pragma unroll
        for (int rg = 0; rg < 4; rg++)
            crv[rg] = bf2f(c_sent[((size_t)(16 * w + 4 * q + rg) * 256 + j) * 1024 + c0 + r]);

        // ---- RIGHT half (independent of other blocks): A = h_sent[:, j, :]
        {
            const unsigned short* aR = h_sent + ((size_t)arow * 256 + j) * 1024 + q * 8;
            const unsigned short* bR = Wpk + ((size_t)(128 + q) * FIVEH + c0 + r) * 8;
#pragma unroll 8
            for (int i = 0; i < 32; i++) {
                const short8 a = *(const short8*)(aR + i * 32);
                short8 b[5];
#pragma unroll
                for (int g = 0; g < 5; g++)
                    b[g] = *(const short8*)(bR + (size_t)i * (4 * FIVEH * 8) + g * 8192);
#pragma unroll
                for (int g = 0; g < 5; g++)
                    acc[g] = __builtin_amdgcn_mfma_f32_16x16x32_bf16(a, b[g], acc[g], 0, 0, 0);
            }
        }

        // ---- grid barrier: wait until all blocks published h(j-1)
        if (tid == 0) {
            const unsigned int tgt = (unsigned int)(NBLK * j);
            while (__hip_atomic_load(ctr, __ATOMIC_RELAXED, __HIP_MEMORY_SCOPE_AGENT) < tgt) {}
            __threadfence();   // acquire: invalidate L1/L2 so h(j-1) reads are fresh
        }
        __syncthreads();

        // ---- LEFT half: A = chain h(j-1); W from LDS (+ small streamed tail)
        {
            const unsigned short* aL = hchain + (size_t)((j - 1) & 1) * 65536
                                              + (size_t)arow * 1024 + q * 8;
            const unsigned short* bLs = Wl + ((size_t)q * 80 + r) * 8;
#pragma unroll 6
            for (int i = 0; i < LDS_KQ / 4; i++) {          // 30 iters from LDS
                const short8 a = *(const short8*)(aL + i * 32);
                short8 b[5];
#pragma unroll
                for (int g = 0; g < 5; g++)
                    b[g] = *(const short8*)(bLs + (size_t)i * (4 * 80 * 8) + g * (16 * 8));
#pragma unroll
                for (int g = 0; g < 5; g++)
                    acc[g] = __builtin_amdgcn_mfma_f32_16x16x32_bf16(a, b[g], acc[g], 0, 0, 0);
            }
            const unsigned short* bLt = Wpk + ((size_t)q * FIVEH + c0 + r) * 8;
#pragma unroll
            for (int i = LDS_KQ / 4; i < 32; i++) {         // kq 120..127 streamed
                const short8 a = *(const short8*)(aL + i * 32);
                short8 b[5];
#pragma unroll
                for (int g = 0; g < 5; g++)
                    b[g] = *(const short8*)(bLt + (size_t)i * (4 * FIVEH * 8) + g * 8192);
#pragma unroll
                for (int g = 0; g < 5; g++)
                    acc[g] = __builtin_amdgcn_mfma_f32_16x16x32_bf16(a, b[g], acc[g], 0, 0, 0);
            }
        }

        // ---- TreeLSTM elementwise; c stays in registers, h published bf16
        unsigned short* hw = hchain + (size_t)(j & 1) * 65536;
#pragma unroll
        for (int rg = 0; rg < 4; rg++) {
            const float g0 = acc[0][rg] + breg[0];
            const float g1 = acc[1][rg] + breg[1];
            const float g2 = acc[2][rg] + breg[2];
            const float g3 = acc[3][rg] + breg[3];
            const float g4 = acc[4][rg] + breg[4];
            const float cn = sigf(g1) * creg[rg] + sigf(g2) * crv[rg] + sigf(g0) * tanhf(g4);
            const float hn = sigf(g3) * tanhf(cn);
            creg[rg] = cn;
            const int m = 16 * w + 4 * q + rg;
            if (j == NSTEPS) out[(size_t)m * 1024 + c0 + r] = hn;
            else             hw[(size_t)m * 1024 + c0 + r] = f2bf(hn);
        }

        if (j < NSTEPS) {
            __syncthreads();                 // drains this block's h stores (vmcnt)
            if (tid == 0) {
                __threadfence();             // release: write back L2 to coherence point
                __hip_atomic_fetch_add(ctr, 1u, __ATOMIC_RELEASE, __HIP_MEMORY_SCOPE_AGENT);
            }
        }
    }
}

// ---------------------------------------------------------------------------
extern "C" void kernel_launch(void* const* d_in, const int* in_sizes, int n_in,
                              void* d_out, int out_size, void* d_ws, size_t ws_size,
                              hipStream_t stream)
{
    (void)in_sizes; (void)n_in; (void)out_size; (void)ws_size;
    const float* sentence = (const float*)d_in[0];
    const float* W_word   = (const float*)d_in[3];
    // d_in[4] b_word: cancels exactly through BatchNorm -> unused
    const float* gamma    = (const float*)d_in[5];
    const float* beta     = (const float*)d_in[6];
    const float* W_reduce = (const float*)d_in[7];
    const float* b_reduce = (const float*)d_in[8];

    // workspace layout (~92.6 MB)
    char* ws = (char*)d_ws;
    size_t off = 0;
    float* sumb   = (float*)(ws + off); off += 8192;
    float* sqb    = (float*)(ws + off); off += 8192;
    float* scale  = (float*)(ws + off); off += 8192;
    float* shift  = (float*)(ws + off); off += 8192;
    unsigned int* ctr = (unsigned int*)(ws + off); off += 256;
    unsigned short* hchain = (unsigned short*)(ws + off); off += 262144;  // [2][64][1024] bf16
    unsigned short* Wwpk = (unsigned short*)(ws + off); off += 4194304;   // [128][2048][8] bf16
    unsigned short* Wpk  = (unsigned short*)(ws + off); off += 20971520;  // [256][5120][8] bf16
    unsigned short* h_sent = (unsigned short*)(ws + off); off += 33554432;
    unsigned short* c_sent = (unsigned short*)(ws + off); off += 33554432;

    pack_w<<<128, 256, 0, stream>>>(W_word, Wwpk, TWOH);
    pack_w<<<256, 256, 0, stream>>>(W_reduce, Wpk, FIVEH);
    zero_stats<<<16, 256, 0, stream>>>(sumb);   // sumb+sqb adjacent
    init_ctr<<<1, 64, 0, stream>>>(ctr);

    gemm_bn_mfma<<<dim3(16, 128), 256, 0, stream>>>(
        sentence, Wwpk, h_sent, c_sent, sumb, sqb);
    bn_finalize<<<8, 256, 0, stream>>>(sumb, sqb, gamma, beta, scale, shift);
    bn_apply<<<16384, 256, 0, stream>>>(h_sent, c_sent, scale, shift);

    spinn_chain<<<NBLK, 256, LDS_BYTES, stream>>>(
        h_sent, c_sent, Wpk, b_reduce, hchain, ctr, (float*)d_out);
}

// Round 2
// 5947.171 us; speedup vs baseline: 1.1447x; 1.0719x over previous
//
#include <hip/hip_runtime.h>
#include <math.h>

// Problem constants: B=64, L=256, E=1024, H=1024
#define TWOH    2048
#define FIVEH   5120
#define NSTEPS  255
#define NBLK    64
#define LDS_KQ  120                       // kq rows of W_l kept in LDS (of 128)
#define LDS_BYTES (LDS_KQ * 80 * 8 * 2)   // 153600 B

typedef __attribute__((ext_vector_type(8))) short short8;
typedef __attribute__((ext_vector_type(8))) unsigned short ushort8;
typedef __attribute__((ext_vector_type(4))) float f32x4;

__device__ __forceinline__ float bf2f(unsigned short u) {
    union { unsigned int i; float f; } v; v.i = ((unsigned int)u) << 16; return v.f;
}
__device__ __forceinline__ unsigned short f2bf(float f) {
    union { float f; unsigned int u; } v; v.f = f;
    return (unsigned short)((v.u + 0x7FFFu + ((v.u >> 16) & 1u)) >> 16);
}
__device__ __forceinline__ short8 cvt8(float4 u0, float4 u1) {
    short8 s;
    s[0] = (short)f2bf(u0.x); s[1] = (short)f2bf(u0.y);
    s[2] = (short)f2bf(u0.z); s[3] = (short)f2bf(u0.w);
    s[4] = (short)f2bf(u1.x); s[5] = (short)f2bf(u1.y);
    s[6] = (short)f2bf(u1.z); s[7] = (short)f2bf(u1.w);
    return s;
}
__device__ __forceinline__ float sigf(float x) { return 1.0f / (1.0f + expf(-x)); }

// 8 cache-bypassing 16B loads (base + 64*i), single in-flight batch.
#define LOADA8(A0,A1,A2,A3,A4,A5,A6,A7, BASE)                                  \
    asm volatile(                                                              \
        "global_load_dwordx4 %0, %8, off sc0 sc1\n\t"                          \
        "global_load_dwordx4 %1, %8, off offset:64 sc0 sc1\n\t"                \
        "global_load_dwordx4 %2, %8, off offset:128 sc0 sc1\n\t"               \
        "global_load_dwordx4 %3, %8, off offset:192 sc0 sc1\n\t"               \
        "global_load_dwordx4 %4, %8, off offset:256 sc0 sc1\n\t"               \
        "global_load_dwordx4 %5, %8, off offset:320 sc0 sc1\n\t"               \
        "global_load_dwordx4 %6, %8, off offset:384 sc0 sc1\n\t"               \
        "global_load_dwordx4 %7, %8, off offset:448 sc0 sc1\n\t"               \
        : "=&v"(A0), "=&v"(A1), "=&v"(A2), "=&v"(A3),                          \
          "=&v"(A4), "=&v"(A5), "=&v"(A6), "=&v"(A7)                           \
        : "v"(BASE) : "memory")

__device__ __forceinline__ void store_short_cc(unsigned short* p, unsigned short v) {
    asm volatile("global_store_short %0, %1, off sc0 sc1"
                 :: "v"(p), "v"((unsigned int)v) : "memory");
}

__global__ void zero_stats(float* __restrict__ p) {
    p[blockIdx.x * 256 + threadIdx.x] = 0.0f;
}
__global__ void init_ctr(unsigned int* __restrict__ c) {
    if (threadIdx.x == 0) *c = 0u;
}

// Pack W[K,N] fp32 -> MFMA-B-fragment layout: out[kq][n][j] = bf16(W[kq*8+j][n])
__global__ void pack_w(const float* __restrict__ W, unsigned short* __restrict__ out, int N)
{
    const int kq = blockIdx.x;
    for (int n = threadIdx.x; n < N; n += 256) {
        ushort8 o;
#pragma unroll
        for (int j = 0; j < 8; j++)
            o[j] = f2bf(W[(size_t)(kq * 8 + j) * N + n]);
        *(ushort8*)&out[((size_t)kq * N + n) * 8] = o;
    }
}

// ---------------------------------------------------------------------------
// P = sentence @ W_word (bias dropped: cancels through BN). Unchanged.
// ---------------------------------------------------------------------------
__global__ __launch_bounds__(256) void gemm_bn_mfma(
    const float* __restrict__ A, const unsigned short* __restrict__ Bpk,
    unsigned short* __restrict__ h_out, unsigned short* __restrict__ c_out,
    float* __restrict__ sumb, float* __restrict__ sqb)
{
    const int tid = threadIdx.x;
    const int wave = tid >> 6, lane = tid & 63;
    const int q = lane >> 4, r = lane & 15;
    const int m0 = blockIdx.y * 128 + (wave >> 1) * 64;
    const int n0 = blockIdx.x * 128 + (wave & 1) * 64;

    f32x4 acc[4][4];
#pragma unroll
    for (int i = 0; i < 4; i++)
#pragma unroll
        for (int j = 0; j < 4; j++) acc[i][j] = (f32x4)0.0f;

    for (int k0 = 0; k0 < 1024; k0 += 32) {
        const int kl = k0 + q * 8;
        short8 a[4], b[4];
#pragma unroll
        for (int mi = 0; mi < 4; mi++) {
            const float* ap = A + (size_t)(m0 + mi * 16 + r) * 1024 + kl;
            a[mi] = cvt8(*(const float4*)ap, *(const float4*)(ap + 4));
        }
#pragma unroll
        for (int ni = 0; ni < 4; ni++)
            b[ni] = *(const short8*)&Bpk[((size_t)(kl >> 3) * TWOH + n0 + ni * 16 + r) * 8];
#pragma unroll
        for (int mi = 0; mi < 4; mi++)
#pragma unroll
            for (int ni = 0; ni < 4; ni++)
                acc[mi][ni] = __builtin_amdgcn_mfma_f32_16x16x32_bf16(a[mi], b[ni], acc[mi][ni], 0, 0, 0);
    }

#pragma unroll
    for (int ni = 0; ni < 4; ni++) {
        float s = 0.0f, qq = 0.0f;
#pragma unroll
        for (int mi = 0; mi < 4; mi++)
#pragma unroll
            for (int rg = 0; rg < 4; rg++) {
                const float v = acc[mi][ni][rg];
                s += v; qq += v * v;
            }
        s += __shfl_xor(s, 16); s += __shfl_xor(s, 32);
        qq += __shfl_xor(qq, 16); qq += __shfl_xor(qq, 32);
        if (lane < 16) {
            atomicAdd(&sumb[n0 + ni * 16 + r], s);
            atomicAdd(&sqb[n0 + ni * 16 + r], qq);
        }
    }

    const bool is_h = (n0 < 1024);
    unsigned short* dst = is_h ? h_out : c_out;
    const int cb = is_h ? n0 : n0 - 1024;
#pragma unroll
    for (int mi = 0; mi < 4; mi++)
#pragma unroll
        for (int rg = 0; rg < 4; rg++) {
            const size_t row = (size_t)(m0 + mi * 16 + q * 4 + rg);
#pragma unroll
            for (int ni = 0; ni < 4; ni++)
                dst[row * 1024 + cb + ni * 16 + r] = f2bf(acc[mi][ni][rg]);
        }
}

__global__ void bn_finalize(const float* __restrict__ sumb, const float* __restrict__ sqb,
                            const float* __restrict__ gamma, const float* __restrict__ beta,
                            float* __restrict__ scale, float* __restrict__ shift)
{
    const int c = blockIdx.x * 256 + threadIdx.x;  // grid 8
    const float inv_n = 1.0f / 16384.0f;
    const float mean = sumb[c] * inv_n;
    const float var = sqb[c] * inv_n - mean * mean;
    const float sc = gamma[c] * rsqrtf(var + 1e-5f);
    scale[c] = sc;
    shift[c] = beta[c] - mean * sc;
}

__global__ void bn_apply(unsigned short* __restrict__ hs, unsigned short* __restrict__ cs,
                         const float* __restrict__ scale, const float* __restrict__ shift)
{
    const bool ish = blockIdx.x < 8192;
    unsigned short* p = ish ? hs : cs;
    const size_t base = ((size_t)(blockIdx.x & 8191) * 256 + threadIdx.x) * 8;
    const int col = (int)(base & 1023);
    const int cb = ish ? col : col + 1024;
    ushort8 v = *(ushort8*)&p[base];
#pragma unroll
    for (int e = 0; e < 8; e++)
        v[e] = f2bf(bf2f(v[e]) * scale[cb + e] + shift[cb + e]);
    *(ushort8*)&p[base] = v;
}

// ---------------------------------------------------------------------------
// Persistent chain kernel, fence-free barrier edition.
//  - NO __threadfence (no buffer_wbl2/buffer_inv, no L2 flush): the only
//    cross-XCD data is hchain + ctr, handled with write-through stores
//    (sc0 sc1) and cache-bypassing loads (sc0 sc1). W / h_sent / c_sent
//    stay warm in per-XCD L2 for the whole kernel.
//  - Barrier: vmcnt(0) drain -> __syncthreads -> RELAXED agent fetch_add;
//    waiters poll with RELAXED agent loads.
//  - Left A (remote h) loaded via 4 batches of 8x dwordx4 sc0 sc1 with one
//    waitcnt + sched_barrier(0) (rule #18), fully in-flight.
//  - Streamed left-tail B fragments (kq 120..127) are step-invariant ->
//    preloaded into registers once before the loop.
// ---------------------------------------------------------------------------
__global__ __launch_bounds__(256, 1) void spinn_chain(
    const unsigned short* __restrict__ h_sent,
    const unsigned short* __restrict__ c_sent,
    const unsigned short* __restrict__ Wpk,   // [256 kq][5120][8] bf16
    const float* __restrict__ b_red,
    unsigned short* __restrict__ hchain,      // [2][64][1024] bf16 ping-pong
    unsigned int* __restrict__ ctr,
    float* __restrict__ out)                  // [64][1024] fp32
{
    extern __shared__ unsigned short Wl[];    // [LDS_KQ][80][8]
    const int tid = threadIdx.x;
    const int w = tid >> 6, lane = tid & 63;
    const int q = lane >> 4, r = lane & 15;
    const int c0 = blockIdx.x * 16;

    // ---- one-time: this block's W_l slice (80 cols x LDS_KQ kq-rows) into LDS
    for (int idx = tid; idx < LDS_KQ * 80; idx += 256) {
        const int kq = idx / 80, c = idx - kq * 80;
        const int g = c >> 4, cc = c & 15;
        *(ushort8*)&Wl[(size_t)idx * 8] =
            *(const ushort8*)&Wpk[((size_t)kq * FIVEH + g * 1024 + c0 + cc) * 8];
    }

    // ---- per-thread constants: bias
    float breg[5];
#pragma unroll
    for (int g = 0; g < 5; g++) breg[g] = b_red[g * 1024 + c0 + r];

    // ---- step-invariant left-tail B fragments (kq 120..127), kept in regs
    short8 btail[2][5];
    {
        const unsigned short* bLt = Wpk + ((size_t)q * FIVEH + c0 + r) * 8;
#pragma unroll
        for (int t = 0; t < 2; t++)
#pragma unroll
            for (int g = 0; g < 5; g++)
                btail[t][g] = *(const short8*)(bLt + (size_t)(LDS_KQ / 4 + t) * (4 * FIVEH * 8) + g * 8192);
    }

    // cells owned by this thread: (m = 16w + 4q + rg, col = c0 + r), rg=0..3
    float creg[4];
#pragma unroll
    for (int rg = 0; rg < 4; rg++) {
        const int m = 16 * w + 4 * q + rg;
        creg[rg] = bf2f(c_sent[(size_t)m * 256 * 1024 + c0 + r]);           // word 0
        store_short_cc(&hchain[(size_t)m * 1024 + c0 + r],
                       h_sent[(size_t)m * 256 * 1024 + c0 + r]);
    }
    asm volatile("s_waitcnt vmcnt(0)" ::: "memory");
    __syncthreads();
    if (tid == 0)
        __hip_atomic_fetch_add(ctr, 1u, __ATOMIC_RELAXED, __HIP_MEMORY_SCOPE_AGENT);

    const int arow = 16 * w + r;  // batch row this lane loads for the A-fragment

    for (int j = 1; j <= NSTEPS; j++) {
        f32x4 acc[5];
#pragma unroll
        for (int g = 0; g < 5; g++) acc[g] = (f32x4)0.0f;

        // prefetch right-child c (word j) for the elementwise phase (warm L2)
        float crv[4];
#pragma unroll
        for (int rg = 0; rg < 4; rg++)
            crv[rg] = bf2f(c_sent[((size_t)(16 * w + 4 * q + rg) * 256 + j) * 1024 + c0 + r]);

        // ---- RIGHT half (independent of other blocks): A = h_sent[:, j, :]
        {
            const unsigned short* aR = h_sent + ((size_t)arow * 256 + j) * 1024 + q * 8;
            const unsigned short* bR = Wpk + ((size_t)(128 + q) * FIVEH + c0 + r) * 8;
#pragma unroll 8
            for (int i = 0; i < 32; i++) {
                const short8 a = *(const short8*)(aR + i * 32);
                short8 b[5];
#pragma unroll
                for (int g = 0; g < 5; g++)
                    b[g] = *(const short8*)(bR + (size_t)i * (4 * FIVEH * 8) + g * 8192);
#pragma unroll
                for (int g = 0; g < 5; g++)
                    acc[g] = __builtin_amdgcn_mfma_f32_16x16x32_bf16(a, b[g], acc[g], 0, 0, 0);
            }
        }

        // ---- grid barrier: wait until all blocks published h(j-1). No fences.
        if (tid == 0) {
            const unsigned int tgt = (unsigned int)(NBLK * j);
            while (__hip_atomic_load(ctr, __ATOMIC_RELAXED, __HIP_MEMORY_SCOPE_AGENT) < tgt) {}
        }
        __syncthreads();

        // ---- LEFT half: A = chain h(j-1) via cache-bypassing loads
        {
            const unsigned short* aL = hchain + (size_t)((j - 1) & 1) * 65536
                                              + (size_t)arow * 1024 + q * 8;
            short8 a[32];
            LOADA8(a[0], a[1], a[2], a[3], a[4], a[5], a[6], a[7], aL);
            LOADA8(a[8], a[9], a[10], a[11], a[12], a[13], a[14], a[15], aL + 256);
            LOADA8(a[16], a[17], a[18], a[19], a[20], a[21], a[22], a[23], aL + 512);
            LOADA8(a[24], a[25], a[26], a[27], a[28], a[29], a[30], a[31], aL + 768);
            asm volatile("s_waitcnt vmcnt(0)" ::: "memory");
            __builtin_amdgcn_sched_barrier(0);

            const unsigned short* bLs = Wl + ((size_t)q * 80 + r) * 8;
#pragma unroll
            for (int i = 0; i < LDS_KQ / 4; i++) {          // 30 iters from LDS
                short8 b[5];
#pragma unroll
                for (int g = 0; g < 5; g++)
                    b[g] = *(const short8*)(bLs + (size_t)i * (4 * 80 * 8) + g * (16 * 8));
#pragma unroll
                for (int g = 0; g < 5; g++)
                    acc[g] = __builtin_amdgcn_mfma_f32_16x16x32_bf16(a[i], b[g], acc[g], 0, 0, 0);
            }
#pragma unroll
            for (int t = 0; t < 2; t++)                     // kq 120..127 from regs
#pragma unroll
                for (int g = 0; g < 5; g++)
                    acc[g] = __builtin_amdgcn_mfma_f32_16x16x32_bf16(a[LDS_KQ / 4 + t], btail[t][g], acc[g], 0, 0, 0);
        }

        // ---- TreeLSTM elementwise; c stays in registers, h published bf16
        unsigned short* hw = hchain + (size_t)(j & 1) * 65536;
#pragma unroll
        for (int rg = 0; rg < 4; rg++) {
            const float g0 = acc[0][rg] + breg[0];
            const float g1 = acc[1][rg] + breg[1];
            const float g2 = acc[2][rg] + breg[2];
            const float g3 = acc[3][rg] + breg[3];
            const float g4 = acc[4][rg] + breg[4];
            const float cn = sigf(g1) * creg[rg] + sigf(g2) * crv[rg] + sigf(g0) * tanhf(g4);
            const float hn = sigf(g3) * tanhf(cn);
            creg[rg] = cn;
            const int m = 16 * w + 4 * q + rg;
            if (j == NSTEPS) out[(size_t)m * 1024 + c0 + r] = hn;
            else             store_short_cc(&hw[(size_t)m * 1024 + c0 + r], f2bf(hn));
        }

        if (j < NSTEPS) {
            asm volatile("s_waitcnt vmcnt(0)" ::: "memory");  // h stores at L3
            __syncthreads();
            if (tid == 0)
                __hip_atomic_fetch_add(ctr, 1u, __ATOMIC_RELAXED, __HIP_MEMORY_SCOPE_AGENT);
        }
    }
}

// ---------------------------------------------------------------------------
extern "C" void kernel_launch(void* const* d_in, const int* in_sizes, int n_in,
                              void* d_out, int out_size, void* d_ws, size_t ws_size,
                              hipStream_t stream)
{
    (void)in_sizes; (void)n_in; (void)out_size; (void)ws_size;
    const float* sentence = (const float*)d_in[0];
    const float* W_word   = (const float*)d_in[3];
    // d_in[4] b_word: cancels exactly through BatchNorm -> unused
    const float* gamma    = (const float*)d_in[5];
    const float* beta     = (const float*)d_in[6];
    const float* W_reduce = (const float*)d_in[7];
    const float* b_reduce = (const float*)d_in[8];

    // workspace layout (~92.6 MB)
    char* ws = (char*)d_ws;
    size_t off = 0;
    float* sumb   = (float*)(ws + off); off += 8192;
    float* sqb    = (float*)(ws + off); off += 8192;
    float* scale  = (float*)(ws + off); off += 8192;
    float* shift  = (float*)(ws + off); off += 8192;
    unsigned int* ctr = (unsigned int*)(ws + off); off += 256;
    unsigned short* hchain = (unsigned short*)(ws + off); off += 262144;  // [2][64][1024] bf16
    unsigned short* Wwpk = (unsigned short*)(ws + off); off += 4194304;   // [128][2048][8] bf16
    unsigned short* Wpk  = (unsigned short*)(ws + off); off += 20971520;  // [256][5120][8] bf16
    unsigned short* h_sent = (unsigned short*)(ws + off); off += 33554432;
    unsigned short* c_sent = (unsigned short*)(ws + off); off += 33554432;

    pack_w<<<128, 256, 0, stream>>>(W_word, Wwpk, TWOH);
    pack_w<<<256, 256, 0, stream>>>(W_reduce, Wpk, FIVEH);
    zero_stats<<<16, 256, 0, stream>>>(sumb);   // sumb+sqb adjacent
    init_ctr<<<1, 64, 0, stream>>>(ctr);

    gemm_bn_mfma<<<dim3(16, 128), 256, 0, stream>>>(
        sentence, Wwpk, h_sent, c_sent, sumb, sqb);
    bn_finalize<<<8, 256, 0, stream>>>(sumb, sqb, gamma, beta, scale, shift);
    bn_apply<<<16384, 256, 0, stream>>>(h_sent, c_sent, scale, shift);

    spinn_chain<<<NBLK, 256, LDS_BYTES, stream>>>(
        h_sent, c_sent, Wpk, b_reduce, hchain, ctr, (float*)d_out);
}